// Round 3
// baseline (14352.467 us; speedup 1.0000x reference)
//
#include <hip/hip_runtime.h>

// CollaborativeExpertsModule — MI355X/gfx950
// Round 2 fix: inputs/outputs are FP32 (per the reference dtypes, as the
// harness contract specifies). Round-2's NaN came from reading fp32 arrays as
// bf16 pairs (mantissa bits -> random exponents -> inf-inf) and writing bf16
// into a float32 d_out. Logits path full fp32 (exact top-2 indices); collab
// path intermediates stored bf16 (0.3% noise << 7% threshold).
// Workspace layout identical to round 2 (52,461,824 B — proven accessible).
// d_out (float): [final 4096*768 | aux | tk_idx 4096*2].

typedef unsigned short u16;
typedef unsigned int u32;

// ---------- bf16 helpers (collab-path storage only) ----------
__device__ __forceinline__ float b2f(u16 v){
  union { u32 u; float f; } x; x.u = ((u32)v) << 16; return x.f;
}
__device__ __forceinline__ u16 f2b(float f){
  union { float f; u32 u; } x; x.f = f;
  u32 u = x.u;
  if ((u & 0x7fffffffu) > 0x7f800000u) return (u16)0x7fc0; // NaN
  return (u16)((u + 0x7fffu + ((u >> 16) & 1u)) >> 16);    // RNE
}
__device__ __forceinline__ float gelu_f(float x){
  return 0.5f * x * (1.f + erff(x * 0.70710678118654752f));
}
__device__ __forceinline__ void ld8bf(const u16* p, float* f){
  uint4 u = *(const uint4*)p;
  f[0]=b2f((u16)(u.x & 0xffff)); f[1]=b2f((u16)(u.x >> 16));
  f[2]=b2f((u16)(u.y & 0xffff)); f[3]=b2f((u16)(u.y >> 16));
  f[4]=b2f((u16)(u.z & 0xffff)); f[5]=b2f((u16)(u.z >> 16));
  f[6]=b2f((u16)(u.w & 0xffff)); f[7]=b2f((u16)(u.w >> 16));
}
__device__ __forceinline__ void ld8f(const float* p, float* f){
  float4 v0 = *(const float4*)p, v1 = *(const float4*)(p + 4);
  f[0]=v0.x; f[1]=v0.y; f[2]=v0.z; f[3]=v0.w;
  f[4]=v1.x; f[5]=v1.y; f[6]=v1.z; f[7]=v1.w;
}

template<int NW>
__device__ __forceinline__ float blockReduceSum(float v, float* red){
  #pragma unroll
  for (int o = 32; o > 0; o >>= 1) v += __shfl_down(v, o, 64);
  const int wv = threadIdx.x >> 6, ln = threadIdx.x & 63;
  __syncthreads();              // protect red[] reuse across calls
  if (ln == 0) red[wv] = v;
  __syncthreads();
  float s = 0.f;
  #pragma unroll
  for (int i = 0; i < NW; i++) s += red[i];
  return s;
}

// ---------- generic tiled GEMM:  C[m,n] = epi( sum_k A[m,k]*B[.,.] ) ----------
// A: fp32 (AF32) or bf16. B: fp32 (BF32) or bf16.
// BT=true : B is (N,K) row-major; BT=false: B is (K,N) row-major.
// Epilogue: optional fp32 bias[n], ACT==1 -> exact GELU, optional bf16
// residual (ldr), output fp32 (OUTF32) or bf16.
// Requires: M%128==0, N%128==0, K%16==0.
template<bool AF32, bool BF32, bool BT, bool BIAS, int ACT, bool RES, bool OUTF32>
__global__ __launch_bounds__(256) void gemm_k(
    const void* __restrict__ Ap, int lda, long long strideA,
    const void* __restrict__ Bp, int ldb, long long strideB,
    void* __restrict__ Cp, int ldc, long long strideC,
    const float* __restrict__ bias, const u16* __restrict__ resid, int ldr,
    int M, int N, int Kd)
{
  __shared__ float As[16][132];
  __shared__ float Bs[16][132];
  const int tid = threadIdx.x;
  const int tx = tid & 15, ty = tid >> 4;
  const int m0 = blockIdx.y * 128, n0 = blockIdx.x * 128;
  const long long z = blockIdx.z;
  const float* A32 = nullptr; const u16* A16 = nullptr;
  if constexpr (AF32) A32 = (const float*)Ap + z * strideA;
  else                A16 = (const u16*)Ap + z * strideA;
  const float* B32 = nullptr; const u16* B16 = nullptr;
  if constexpr (BF32) B32 = (const float*)Bp + z * strideB;
  else                B16 = (const u16*)Bp + z * strideB;

  float acc[8][8];
  #pragma unroll
  for (int i = 0; i < 8; i++)
    #pragma unroll
    for (int j = 0; j < 8; j++) acc[i][j] = 0.f;

  const int ar = tid >> 1, ak = (tid & 1) * 8;      // A / B^T staging: row, k-chunk
  const int bkr = tid >> 4, bnc = (tid & 15) * 8;   // B (K,N) staging

  for (int kt = 0; kt < Kd; kt += 16){
    __syncthreads();
    { // stage A -> As[k][m]
      float f[8];
      if constexpr (AF32) ld8f (A32 + (size_t)(m0 + ar) * lda + kt + ak, f);
      else                ld8bf(A16 + (size_t)(m0 + ar) * lda + kt + ak, f);
      #pragma unroll
      for (int j = 0; j < 8; j++) As[ak + j][ar] = f[j];
    }
    if constexpr (BT){ // B^T (N,K): same pattern as A -> Bs[k][n]
      float f[8];
      if constexpr (BF32) ld8f (B32 + (size_t)(n0 + ar) * ldb + kt + ak, f);
      else                ld8bf(B16 + (size_t)(n0 + ar) * ldb + kt + ak, f);
      #pragma unroll
      for (int j = 0; j < 8; j++) Bs[ak + j][ar] = f[j];
    } else {           // B (K,N): contiguous n -> Bs[k][n]
      float f[8];
      if constexpr (BF32) ld8f (B32 + (size_t)(kt + bkr) * ldb + n0 + bnc, f);
      else                ld8bf(B16 + (size_t)(kt + bkr) * ldb + n0 + bnc, f);
      #pragma unroll
      for (int j = 0; j < 8; j++) Bs[bkr][bnc + j] = f[j];
    }
    __syncthreads();
    #pragma unroll
    for (int k = 0; k < 16; k++){
      float av[8], bv[8];
      const float4 a0 = *(const float4*)&As[k][ty * 8];
      const float4 a1 = *(const float4*)&As[k][ty * 8 + 4];
      const float4 b0 = *(const float4*)&Bs[k][tx * 8];
      const float4 b1 = *(const float4*)&Bs[k][tx * 8 + 4];
      av[0]=a0.x; av[1]=a0.y; av[2]=a0.z; av[3]=a0.w;
      av[4]=a1.x; av[5]=a1.y; av[6]=a1.z; av[7]=a1.w;
      bv[0]=b0.x; bv[1]=b0.y; bv[2]=b0.z; bv[3]=b0.w;
      bv[4]=b1.x; bv[5]=b1.y; bv[6]=b1.z; bv[7]=b1.w;
      #pragma unroll
      for (int i = 0; i < 8; i++)
        #pragma unroll
        for (int j = 0; j < 8; j++)
          acc[i][j] = fmaf(av[i], bv[j], acc[i][j]);
    }
  }

  float* C32 = nullptr; u16* C16 = nullptr;
  if constexpr (OUTF32) C32 = (float*)Cp + z * strideC;
  else                  C16 = (u16*)Cp + z * strideC;
  float bv[8];
  if constexpr (BIAS){
    #pragma unroll
    for (int j = 0; j < 8; j++) bv[j] = bias[n0 + tx * 8 + j];
  }
  #pragma unroll
  for (int i = 0; i < 8; i++){
    const int m = m0 + ty * 8 + i;
    #pragma unroll
    for (int j = 0; j < 8; j++){
      const int n = n0 + tx * 8 + j;
      float v = acc[i][j];
      if constexpr (BIAS) v += bv[j];
      if constexpr (ACT == 1) v = gelu_f(v);
      if constexpr (RES) v += b2f(resid[(size_t)m * ldr + n]);
      if constexpr (OUTF32) C32[(size_t)m * ldc + n] = v;
      else                  C16[(size_t)m * ldc + n] = f2b(v);
    }
  }
  (void)M; (void)N;
}

// ---------- elementwise SwiGLU: h = silu(g)*u (fp32, in-place into g ok) ----------
__global__ void silu_k(const float* __restrict__ g, const float* __restrict__ u,
                       float* __restrict__ h, int n){
  const int i = blockIdx.x * 256 + threadIdx.x;
  if (i < n){ const float x = g[i]; h[i] = (x / (1.f + expf(-x))) * u[i]; }
}

// ---------- router self-attention over E=8 experts, 12 heads, hd=64 (fp32) ----------
__global__ __launch_bounds__(128) void router_attn(const float* __restrict__ qkv,
                                                   float* __restrict__ attn_o){
  __shared__ float L[8 * 1536];     // phase1: q||k ; phase2 reuse: v (8*768)
  __shared__ float Ps[96][8];
  const int t = blockIdx.x, tid = threadIdx.x;
  const float* src = qkv + (size_t)t * 8 * 2304;
  for (int i = tid; i < 3072; i += 128){          // 8*1536/4 float4s
    const int e = i / 384, c4 = i - e * 384;
    ((float4*)L)[i] = ((const float4*)(src + (size_t)e * 2304))[c4];
  }
  __syncthreads();
  if (tid < 96){
    const int h = tid >> 3, e = tid & 7;
    const float* q = L + e * 1536 + h * 64;
    float s[8]; float mx = -1e30f;
    #pragma unroll
    for (int e2 = 0; e2 < 8; e2++){
      const float* kk = L + e2 * 1536 + 768 + h * 64;
      float acc = 0.f;
      #pragma unroll
      for (int d = 0; d < 64; d++) acc = fmaf(q[d], kk[d], acc);
      s[e2] = acc * 0.125f;                       // 1/sqrt(64)
      mx = fmaxf(mx, s[e2]);
    }
    float den = 0.f;
    #pragma unroll
    for (int e2 = 0; e2 < 8; e2++){ s[e2] = expf(s[e2] - mx); den += s[e2]; }
    const float inv = 1.f / den;
    #pragma unroll
    for (int e2 = 0; e2 < 8; e2++) Ps[tid][e2] = s[e2] * inv;
  }
  __syncthreads();
  for (int i = tid; i < 1536; i += 128){          // v: 8*768/4 float4s
    const int e = i / 192, c4 = i - e * 192;
    ((float4*)L)[i] = ((const float4*)(src + (size_t)e * 2304 + 1536))[c4];
  }
  __syncthreads();
  if (tid < 96){
    const int h = tid >> 3, e = tid & 7;
    float p[8];
    #pragma unroll
    for (int e2 = 0; e2 < 8; e2++) p[e2] = Ps[tid][e2];
    float* dst = attn_o + ((size_t)t * 8 + e) * 768 + h * 64;
    for (int d = 0; d < 64; d++){
      float acc = 0.f;
      #pragma unroll
      for (int e2 = 0; e2 < 8; e2++) acc = fmaf(p[e2], L[e2 * 768 + h * 64 + d], acc);
      dst[d] = acc;
    }
  }
}

// ---------- router tail (per 256-token chunk): RMS(ctx+ef), mean over experts,
// logits, softmax/usage, top-2, tk_probs, gather sf(bf16), tk_idx -> d_out ----
__global__ __launch_bounds__(256) void router_final(
    const float* __restrict__ proj, const float* __restrict__ eoc,
    const float* __restrict__ rnw, const float* __restrict__ gw,
    int t0, float* __restrict__ usage, float* __restrict__ tkp,
    u16* __restrict__ sf, float* __restrict__ oidx)
{
  const int tl = blockIdx.x, t = t0 + tl, tid = threadIdx.x;
  __shared__ float red[4];
  __shared__ float lg[8];
  __shared__ int sidx[2];
  __shared__ float csum[768];
  for (int i = tid; i < 768; i += 256) csum[i] = 0.f;
  __syncthreads();
  for (int e = 0; e < 8; e++){
    const float* pr = proj + ((size_t)tl * 8 + e) * 768;
    const float* er = eoc  + ((size_t)tl * 8 + e) * 768;
    float v[3]; float ss = 0.f;
    #pragma unroll
    for (int i = 0; i < 3; i++){ const int c = tid + i * 256; v[i] = pr[c] + er[c]; ss += v[i] * v[i]; }
    ss = blockReduceSum<4>(ss, red);
    const float sc = 1.f / sqrtf(ss * (1.f / 768.f) + 1e-5f);
    #pragma unroll
    for (int i = 0; i < 3; i++){ const int c = tid + i * 256; csum[c] += v[i] * sc * rnw[c]; }
  }
  for (int j = 0; j < 8; j++){
    float p = 0.f;
    #pragma unroll
    for (int i = 0; i < 3; i++){ const int c = tid + i * 256; p += csum[c] * gw[j * 768 + c]; }
    p = blockReduceSum<4>(p, red);
    if (tid == 0) lg[j] = p * 0.125f;   // mean over 8 experts
  }
  __syncthreads();
  if (tid == 0){
    float mx = -1e30f;
    for (int j = 0; j < 8; j++) mx = fmaxf(mx, lg[j]);
    float ex[8], den = 0.f;
    for (int j = 0; j < 8; j++){ ex[j] = expf(lg[j] - mx); den += ex[j]; }
    const float inv = 1.f / den;
    for (int j = 0; j < 8; j++) atomicAdd(&usage[j], ex[j] * inv);
    int i0 = 0; float l0 = lg[0];
    for (int j = 1; j < 8; j++) if (lg[j] > l0){ l0 = lg[j]; i0 = j; }
    int i1 = -1; float l1 = -1e30f;
    for (int j = 0; j < 8; j++) if (j != i0 && lg[j] > l1){ l1 = lg[j]; i1 = j; }
    const float e1 = expf(l1 - l0);
    const float p0 = 1.f / (1.f + e1);
    tkp[(size_t)t * 2]     = p0;
    tkp[(size_t)t * 2 + 1] = e1 * p0;
    sidx[0] = i0; sidx[1] = i1;
    oidx[(size_t)t * 2]     = (float)i0;
    oidx[(size_t)t * 2 + 1] = (float)i1;
  }
  __syncthreads();
  const int i0 = sidx[0], i1 = sidx[1];
  #pragma unroll
  for (int i = 0; i < 3; i++){
    const int c = tid + i * 256;
    sf[((size_t)t * 2 + 0) * 768 + c] = f2b(eoc[((size_t)tl * 8 + i0) * 768 + c]);
    sf[((size_t)t * 2 + 1) * 768 + c] = f2b(eoc[((size_t)tl * 8 + i1) * 768 + c]);
  }
}

// ---------- collaborative attention: L=2, 2 heads, hd=384 (bf16 io) ----------
__global__ __launch_bounds__(128) void collab_attn(
    const u16* __restrict__ qkv, u16* __restrict__ attn_o, float* __restrict__ divsum)
{
  const int t = blockIdx.x, tid = threadIdx.x;
  __shared__ float L[4608];     // 2 rows x 2304
  __shared__ float P[8];        // [h][i][j]
  __shared__ float red[2];
  const u16* src = qkv + (size_t)t * 4608;
  for (int i = tid; i < 4608; i += 128) L[i] = b2f(src[i]);
  __syncthreads();
  for (int hij = 0; hij < 8; hij++){
    const int h = hij >> 2, qi = (hij >> 1) & 1, kj = hij & 1;
    const float* q = L + qi * 2304 + h * 384;
    const float* k = L + kj * 2304 + 768 + h * 384;
    float acc = 0.f;
    for (int d = tid; d < 384; d += 128) acc += q[d] * k[d];
    acc = blockReduceSum<2>(acc, red);
    if (tid == 0) P[hij] = acc;
  }
  __syncthreads();
  if (tid == 0){
    const float scale = 0.051031036307982884f;  // 1/sqrt(384)
    float aw[2][2] = {{0.f,0.f},{0.f,0.f}};
    for (int h = 0; h < 2; h++)
      for (int i = 0; i < 2; i++){
        const float s0 = P[h*4 + i*2 + 0] * scale, s1 = P[h*4 + i*2 + 1] * scale;
        const float m = fmaxf(s0, s1);
        const float e0 = expf(s0 - m), e1 = expf(s1 - m), inv = 1.f / (e0 + e1);
        P[h*4 + i*2 + 0] = e0 * inv; P[h*4 + i*2 + 1] = e1 * inv;
        aw[i][0] += 0.5f * e0 * inv; aw[i][1] += 0.5f * e1 * inv;
      }
    float ent = 0.f;
    for (int i = 0; i < 2; i++)
      for (int j = 0; j < 2; j++) ent -= aw[i][j] * logf(aw[i][j] + 1e-9f);
    atomicAdd(divsum, ent);
  }
  __syncthreads();
  for (int c = tid; c < 768; c += 128){
    const int h = c / 384;
    const float v0 = L[1536 + c], v1 = L[3840 + c];
    const float o0 = P[h*4 + 0] * v0 + P[h*4 + 1] * v1;
    const float o1 = P[h*4 + 2] * v0 + P[h*4 + 3] * v1;
    attn_o[((size_t)t * 2 + 0) * 768 + c] = f2b(o0);
    attn_o[((size_t)t * 2 + 1) * 768 + c] = f2b(o1);
  }
}

// ---------- RMS(a+b)*w -> bf16  (a,b bf16; w fp32) ----------
__global__ __launch_bounds__(256) void rms_k(const u16* __restrict__ a, const u16* __restrict__ b,
                                             const float* __restrict__ wt, u16* __restrict__ o){
  const int r = blockIdx.x, tid = threadIdx.x;
  __shared__ float red[4];
  float v[3]; float ss = 0.f;
  #pragma unroll
  for (int i = 0; i < 3; i++){
    const int c = tid + i * 256;
    v[i] = b2f(a[(size_t)r * 768 + c]) + b2f(b[(size_t)r * 768 + c]);
    ss += v[i] * v[i];
  }
  ss = blockReduceSum<4>(ss, red);
  const float sc = 1.f / sqrtf(ss * (1.f / 768.f) + 1e-5f);
  #pragma unroll
  for (int i = 0; i < 3; i++){
    const int c = tid + i * 256;
    o[(size_t)r * 768 + c] = f2b(v[i] * sc * wt[c]);
  }
}

// ---------- y[tl] = p0*refined[tl,0] + p1*refined[tl,1]  (half-local) ----------
__global__ void wsum(const u16* __restrict__ refined, const float* __restrict__ tkp,
                     u16* __restrict__ y){
  const int idx = blockIdx.x * 256 + threadIdx.x;   // exactly 2048*768
  const int t = idx / 768, c = idx - t * 768;
  const float r0 = b2f(refined[((size_t)t * 2) * 768 + c]);
  const float r1 = b2f(refined[((size_t)t * 2 + 1) * 768 + c]);
  y[idx] = f2b(tkp[t * 2] * r0 + tkp[t * 2 + 1] * r1);
}

// ---------- aux ----------
__global__ void aux_k(const float* __restrict__ usage, const float* __restrict__ divsum,
                      float* __restrict__ out){
  if (threadIdx.x == 0 && blockIdx.x == 0){
    float u[8], s = 0.f;
    for (int e = 0; e < 8; e++){ u[e] = usage[e] * (1.f / 4096.f); s += u[e]; }
    const float mean = s * 0.125f;
    float bal = 0.f;
    for (int e = 0; e < 8; e++){ const float d = u[e] - mean; bal += d * d; }
    bal *= 0.125f;
    const float div = divsum[0] * (1.f / 8192.f);
    out[0] = 0.1f * (0.01f * div + 0.01f * bal);
  }
}

__global__ void zero_k(float* p, int n){
  const int i = blockIdx.x * 64 + threadIdx.x;
  if (i < n) p[i] = 0.f;
}

// =====================================================================
extern "C" void kernel_launch(void* const* d_in, const int* in_sizes, int n_in,
                              void* d_out, int out_size, void* d_ws, size_t ws_size,
                              hipStream_t stream)
{
  (void)in_sizes; (void)n_in; (void)out_size; (void)ws_size;
  const float* x       = (const float*)d_in[0];   // (4096, 768)
  const float* w1      = (const float*)d_in[1];   // (8, 768, 2048)
  const float* w3      = (const float*)d_in[2];   // (8, 768, 2048)
  const float* w2      = (const float*)d_in[3];   // (8, 2048, 768)
  const float* r_in_w  = (const float*)d_in[4];   // (2304, 768)
  const float* r_in_b  = (const float*)d_in[5];   // (2304,)
  const float* r_out_w = (const float*)d_in[6];   // (768, 768)
  const float* r_out_b = (const float*)d_in[7];
  const float* r_norm_w= (const float*)d_in[8];
  const float* gate_w  = (const float*)d_in[9];   // (8, 768)
  const float* c_in_w  = (const float*)d_in[10];
  const float* c_in_b  = (const float*)d_in[11];
  const float* c_out_w = (const float*)d_in[12];
  const float* c_out_b = (const float*)d_in[13];
  const float* c_norm_w= (const float*)d_in[14];
  const float* ffn_w1  = (const float*)d_in[15];
  const float* ffn_w2  = (const float*)d_in[16];
  const float* o_w     = (const float*)d_in[17];

  // ---- workspace layout (total 52,461,824 B — same extent as round 2) ----
  char* wsb   = (char*)d_ws;
  char* arena = wsb;                        // 33,554,432 B, time-shared
  float* eoc  = (float*)(wsb + 33554432);   //  6,291,456 B : chunk expert_out fp32 (256 tok x 8 x 768)
  u16*   sf   = (u16*)  (wsb + 39845888);   // 12,582,912 B : gathered experts bf16 (8192 x 768)
  float* tkp  = (float*)(wsb + 52428800);   //     32,768 B : top-2 probs fp32
  float* usage= (float*)(wsb + 52461568);   //        256 B : usage[8] + divsum at [8]

  // Phase-A aliases (fp32): gate/up first; qkv/attn/proj reuse after.
  float* gateb = (float*)(arena);             // 16,777,216 B (8 x 256 x 2048 fp32)
  float* upb   = (float*)(arena + 16777216);  // 16,777,216 B
  float* qkvr  = (float*)(arena);             // 18,874,368 B (2048 x 2304 fp32)
  float* aor   = (float*)(arena + 18874368);  //  6,291,456 B (2048 x 768 fp32)
  float* projr = (float*)(arena + 25165824);  //  6,291,456 B -> ends 31,457,280 OK

  // Phase-B aliases (bf16, per 2048-token half = 4096 rows)
  u16* qkvc  = (u16*)(arena);                 // 18,874,368 B (4096 x 2304)
  u16* aoc   = (u16*)(arena + 18874368);      //  6,291,456 B
  u16* projc = (u16*)(arena + 25165824);      //  6,291,456 B -> ends 31,457,280 OK
  u16* aob   = (u16*)(arena);                 //  6,291,456 B (qkvc dead by then)
  u16* t1b   = (u16*)(arena + 6291456);       //  6,291,456 B
  u16* refb  = (u16*)(arena + 12582912);      //  6,291,456 B -> ends 18,874,368
  u16* ybuf  = (u16*)(arena + 18874368);      //  3,145,728 B (aoc dead by then)

  float* outp    = (float*)d_out;
  float* out_aux = outp + (size_t)4096*768;
  float* out_idx = out_aux + 1;

  zero_k<<<1, 64, 0, stream>>>(usage, 16);

  // -------- Phase A: logits path, 16 chunks x 256 tokens (fp32) --------
  for (int cch = 0; cch < 16; cch++){
    const int t0 = cch * 256;
    // gate = x @ w1[e]  (NN), batched over experts via z
    gemm_k<true,true,false,false,0,false,true><<<dim3(16,2,8),256,0,stream>>>(
      x + (size_t)t0*768, 768, 0LL, w1, 2048, 1572864LL,
      gateb, 2048, 524288LL, nullptr, nullptr, 0, 256, 2048, 768);
    // up = x @ w3[e]
    gemm_k<true,true,false,false,0,false,true><<<dim3(16,2,8),256,0,stream>>>(
      x + (size_t)t0*768, 768, 0LL, w3, 2048, 1572864LL,
      upb, 2048, 524288LL, nullptr, nullptr, 0, 256, 2048, 768);
    // hidden = silu(gate)*up  (in-place into gateb)
    silu_k<<<16384, 256, 0, stream>>>(gateb, upb, gateb, 4194304);
    // expert_out chunk: rows (tok*8+e) via ldc=6144, z-offset strideC=768
    gemm_k<true,true,false,false,0,false,true><<<dim3(6,2,8),256,0,stream>>>(
      gateb, 2048, 524288LL, w2, 768, 1572864LL,
      eoc, 6144, 768LL, nullptr, nullptr, 0, 256, 768, 2048);
    // router qkv = ef @ r_in_w^T + b  (2048 rows)
    gemm_k<true,true,true,true,0,false,true><<<dim3(18,16,1),256,0,stream>>>(
      eoc, 768, 0LL, r_in_w, 768, 0LL,
      qkvr, 2304, 0LL, r_in_b, nullptr, 0, 2048, 2304, 768);
    router_attn<<<256, 128, 0, stream>>>(qkvr, aor);
    // out proj
    gemm_k<true,true,true,true,0,false,true><<<dim3(6,16,1),256,0,stream>>>(
      aor, 768, 0LL, r_out_w, 768, 0LL,
      projr, 768, 0LL, r_out_b, nullptr, 0, 2048, 768, 768);
    router_final<<<256, 256, 0, stream>>>(projr, eoc, r_norm_w, gate_w, t0,
                                          usage, tkp, sf, out_idx);
  }

  // -------- Phase B: collaborative path (bf16 storage), 2 halves --------
  for (int h = 0; h < 2; h++){
    const u16* sf_h = sf + (size_t)h * 2048 * 2 * 768;
    gemm_k<false,true,true,true,0,false,false><<<dim3(18,32,1),256,0,stream>>>(
      sf_h, 768, 0LL, c_in_w, 768, 0LL, qkvc, 2304, 0LL, c_in_b, nullptr, 0, 4096, 2304, 768);
    collab_attn<<<2048, 128, 0, stream>>>(qkvc, aoc, usage + 8);
    gemm_k<false,true,true,true,0,false,false><<<dim3(6,32,1),256,0,stream>>>(
      aoc, 768, 0LL, c_out_w, 768, 0LL, projc, 768, 0LL, c_out_b, nullptr, 0, 4096, 768, 768);
    rms_k<<<4096, 256, 0, stream>>>(projc, sf_h, c_norm_w, aob);
    // t1 = gelu(ao @ ffn_w1^T)
    gemm_k<false,true,true,false,1,false,false><<<dim3(6,32,1),256,0,stream>>>(
      aob, 768, 0LL, ffn_w1, 768, 0LL, t1b, 768, 0LL, nullptr, nullptr, 0, 4096, 768, 768);
    // refined = t1 @ ffn_w2^T + ao
    gemm_k<false,true,true,false,0,true,false><<<dim3(6,32,1),256,0,stream>>>(
      t1b, 768, 0LL, ffn_w2, 768, 0LL, refb, 768, 0LL, nullptr, aob, 768, 4096, 768, 768);
    wsum<<<6144, 256, 0, stream>>>(refb, tkp + (size_t)h * 4096, ybuf);
    // final = y @ o_w^T  -> d_out (fp32)
    gemm_k<false,true,true,false,0,false,true><<<dim3(6,16,1),256,0,stream>>>(
      ybuf, 768, 0LL, o_w, 768, 0LL, outp + (size_t)h * 2048 * 768, 768, 0LL,
      nullptr, nullptr, 0, 2048, 768, 768);
  }
  aux_k<<<1, 64, 0, stream>>>(usage, usage + 8, out_aux);
}

// Round 4
// 6066.241 us; speedup vs baseline: 2.3660x; 2.3660x over previous
//
#include <hip/hip_runtime.h>

// CollaborativeExpertsModule — MI355X/gfx950
// Round 4: MFMA rewrite. Logits path uses split-fp16 (hi/lo, 3-pass Ozaki)
// MFMA GEMMs -> ~fp32 precision (logit err ~1e-6, exact top-2 preserved).
// Collab path: 1-pass fp16-hi MFMA, fp32 intermediates. Split happens in
// registers during LDS staging from fp32 sources — no converted weight
// copies. Workspace layout byte-identical to round 3 (52,461,824 B, proven).
// d_out (float): [final 4096*768 | aux | tk_idx 4096*2].

typedef unsigned short u16;
typedef unsigned int u32;
typedef _Float16 f16;
typedef f16 f16x4 __attribute__((ext_vector_type(4)));
typedef f16 f16x8 __attribute__((ext_vector_type(8)));
typedef float f32x4 __attribute__((ext_vector_type(4)));

__device__ __forceinline__ float b2f(u16 v){
  union { u32 u; float f; } x; x.u = ((u32)v) << 16; return x.f;
}
__device__ __forceinline__ u16 f2b(float f){
  union { float f; u32 u; } x; x.f = f;
  u32 u = x.u;
  if ((u & 0x7fffffffu) > 0x7f800000u) return (u16)0x7fc0;
  return (u16)((u + 0x7fffu + ((u >> 16) & 1u)) >> 16);
}
__device__ __forceinline__ float gelu_f(float x){
  return 0.5f * x * (1.f + erff(x * 0.70710678118654752f));
}

template<int NW>
__device__ __forceinline__ float blockReduceSum(float v, float* red){
  #pragma unroll
  for (int o = 32; o > 0; o >>= 1) v += __shfl_down(v, o, 64);
  const int wv = threadIdx.x >> 6, ln = threadIdx.x & 63;
  __syncthreads();
  if (ln == 0) red[wv] = v;
  __syncthreads();
  float s = 0.f;
  #pragma unroll
  for (int i = 0; i < NW; i++) s += red[i];
  return s;
}

// =====================  MFMA GEMM  =====================
// C[m,n] = epi( sum_k A[m,k] * B[k,n] ), 128x128 tile, BK=32, 256 thr (4 waves),
// each wave owns a 64x64 quadrant = 4x4 mfma_f32_16x16x32_f16 tiles.
// AK: 0 = A fp32, 1 = A bf16(u16).  SPLIT: hi/lo 3-pass (requires AK==0, B fp32).
// BT: B is (N,K) row-major; else (K,N).  DUAL: z<zs -> B1/C1 else B2/C2.
// Requires M%128==0, N%128==0, K%32==0.
// LDS rows padded to 40 halfs (80B): frag ds_read_b128 16B-aligned, ~2-way max.
template<int AK, bool SPLIT, bool BT, bool BIAS, int ACT, bool RES, bool DUAL>
__global__ __launch_bounds__(256) void mgemm(
    const void* __restrict__ Ap, int lda, long long strideA,
    const float* __restrict__ B1, const float* __restrict__ B2, int ldb, long long strideB,
    float* __restrict__ C1, float* __restrict__ C2, int ldc, long long strideC,
    const float* __restrict__ bias, const float* __restrict__ resid, int ldr,
    int Kd, int zs)
{
  __shared__ f16 AsH[128*40];
  __shared__ f16 BsH[128*40];
  __shared__ f16 AsL[SPLIT ? 128*40 : 4];
  __shared__ f16 BsL[SPLIT ? 128*40 : 4];

  const int tid = threadIdx.x;
  const int m0 = blockIdx.y * 128, n0 = blockIdx.x * 128;
  const int z = blockIdx.z;
  int zi = z;
  const float* Bz; float* Cz;
  if constexpr (DUAL){
    if (z < zs){ zi = z;      Bz = B1 + (long long)zi*strideB; Cz = C1 + (long long)zi*strideC; }
    else       { zi = z - zs; Bz = B2 + (long long)zi*strideB; Cz = C2 + (long long)zi*strideC; }
  } else { Bz = B1 + (long long)z*strideB; Cz = C1 + (long long)z*strideC; }
  const float* A32 = (const float*)Ap + (AK==0 ? (long long)zi*strideA : 0);
  const u16*   A16 = (const u16*)Ap   + (AK==1 ? (long long)zi*strideA : 0);

  f32x4 acc[4][4];
  #pragma unroll
  for (int i = 0; i < 4; i++)
    #pragma unroll
    for (int j = 0; j < 4; j++){ acc[i][j][0]=0.f; acc[i][j][1]=0.f; acc[i][j][2]=0.f; acc[i][j][3]=0.f; }

  const int ln = tid & 63, wv = tid >> 6;
  const int wm = (wv >> 1) * 64, wn = (wv & 1) * 64;
  const int fr = ln & 15, fq = ln >> 4;

  for (int kt = 0; kt < Kd; kt += 32){
    __syncthreads();
    { // ---- stage A tile (128 x 32) ----
      const int r = tid >> 1, kc = (tid & 1) * 16;
      if constexpr (AK == 0){
        const float* src = A32 + (size_t)(m0 + r) * lda + kt + kc;
        #pragma unroll
        for (int j = 0; j < 4; j++){
          const float4 v = ((const float4*)src)[j];
          f16x4 h; h[0]=(f16)v.x; h[1]=(f16)v.y; h[2]=(f16)v.z; h[3]=(f16)v.w;
          *(f16x4*)&AsH[r*40 + kc + j*4] = h;
          if constexpr (SPLIT){
            f16x4 l;
            l[0]=(f16)(v.x-(float)h[0]); l[1]=(f16)(v.y-(float)h[1]);
            l[2]=(f16)(v.z-(float)h[2]); l[3]=(f16)(v.w-(float)h[3]);
            *(f16x4*)&AsL[r*40 + kc + j*4] = l;
          }
        }
      } else {
        const u16* src = A16 + (size_t)(m0 + r) * lda + kt + kc;
        #pragma unroll
        for (int j = 0; j < 2; j++){
          const uint4 v = ((const uint4*)src)[j];
          f16x8 h;
          h[0]=(f16)b2f((u16)(v.x & 0xffff)); h[1]=(f16)b2f((u16)(v.x >> 16));
          h[2]=(f16)b2f((u16)(v.y & 0xffff)); h[3]=(f16)b2f((u16)(v.y >> 16));
          h[4]=(f16)b2f((u16)(v.z & 0xffff)); h[5]=(f16)b2f((u16)(v.z >> 16));
          h[6]=(f16)b2f((u16)(v.w & 0xffff)); h[7]=(f16)b2f((u16)(v.w >> 16));
          *(f16x8*)&AsH[r*40 + kc + j*8] = h;
        }
      }
    }
    if constexpr (BT){ // ---- stage B^T (N,K): rows are n ----
      const int r = tid >> 1, kc = (tid & 1) * 16;
      const float* src = Bz + (size_t)(n0 + r) * ldb + kt + kc;
      #pragma unroll
      for (int j = 0; j < 4; j++){
        const float4 v = ((const float4*)src)[j];
        f16x4 h; h[0]=(f16)v.x; h[1]=(f16)v.y; h[2]=(f16)v.z; h[3]=(f16)v.w;
        *(f16x4*)&BsH[r*40 + kc + j*4] = h;
        if constexpr (SPLIT){
          f16x4 l;
          l[0]=(f16)(v.x-(float)h[0]); l[1]=(f16)(v.y-(float)h[1]);
          l[2]=(f16)(v.z-(float)h[2]); l[3]=(f16)(v.w-(float)h[3]);
          *(f16x4*)&BsL[r*40 + kc + j*4] = l;
        }
      }
    } else { // ---- stage B (K,N): transpose into Bs[n][k] ----
      const int i = tid & 15, kk = (tid >> 4) * 2;
      #pragma unroll
      for (int kr = 0; kr < 2; kr++){
        const float* src = Bz + (size_t)(kt + kk + kr) * ldb + n0 + i;
        #pragma unroll
        for (int j = 0; j < 8; j++){
          const float v = src[16*j];
          const f16 h = (f16)v;
          BsH[(i + 16*j)*40 + kk + kr] = h;
          if constexpr (SPLIT) BsL[(i + 16*j)*40 + kk + kr] = (f16)(v - (float)h);
        }
      }
    }
    __syncthreads();
    // ---- compute: 16 MFMA per pass ----
    f16x8 aH[4], bH[4];
    #pragma unroll
    for (int i = 0; i < 4; i++) aH[i] = *(const f16x8*)&AsH[(wm + i*16 + fr)*40 + fq*8];
    #pragma unroll
    for (int j = 0; j < 4; j++) bH[j] = *(const f16x8*)&BsH[(wn + j*16 + fr)*40 + fq*8];
    #pragma unroll
    for (int i = 0; i < 4; i++)
      #pragma unroll
      for (int j = 0; j < 4; j++)
        acc[i][j] = __builtin_amdgcn_mfma_f32_16x16x32_f16(aH[i], bH[j], acc[i][j], 0, 0, 0);
    if constexpr (SPLIT){
      f16x8 aL[4], bL[4];
      #pragma unroll
      for (int i = 0; i < 4; i++) aL[i] = *(const f16x8*)&AsL[(wm + i*16 + fr)*40 + fq*8];
      #pragma unroll
      for (int j = 0; j < 4; j++) bL[j] = *(const f16x8*)&BsL[(wn + j*16 + fr)*40 + fq*8];
      #pragma unroll
      for (int i = 0; i < 4; i++)
        #pragma unroll
        for (int j = 0; j < 4; j++){
          acc[i][j] = __builtin_amdgcn_mfma_f32_16x16x32_f16(aH[i], bL[j], acc[i][j], 0, 0, 0);
          acc[i][j] = __builtin_amdgcn_mfma_f32_16x16x32_f16(aL[i], bH[j], acc[i][j], 0, 0, 0);
        }
    }
  }

  // ---- epilogue: C/D layout col=lane&15, row=quad*4+reg (m89-verified) ----
  #pragma unroll
  for (int j = 0; j < 4; j++){
    const int n = n0 + wn + j*16 + fr;
    float bv = 0.f;
    if constexpr (BIAS) bv = bias[n];
    #pragma unroll
    for (int i = 0; i < 4; i++){
      #pragma unroll
      for (int r = 0; r < 4; r++){
        const int m = m0 + wm + i*16 + fq*4 + r;
        float v = acc[i][j][r];
        if constexpr (BIAS) v += bv;
        if constexpr (ACT == 1) v = gelu_f(v);
        if constexpr (RES) v += resid[(size_t)m * ldr + n];
        Cz[(size_t)m * ldc + n] = v;
      }
    }
  }
}

// ---------- elementwise SwiGLU: h = silu(g)*u ----------
__global__ void silu_k(const float* __restrict__ g, const float* __restrict__ u,
                       float* __restrict__ h, int n){
  const int i = blockIdx.x * 256 + threadIdx.x;
  if (i < n){ const float x = g[i]; h[i] = (x / (1.f + expf(-x))) * u[i]; }
}

// ---------- router self-attention over E=8 experts, 12 heads, hd=64 (fp32) ----------
__global__ __launch_bounds__(128) void router_attn(const float* __restrict__ qkv,
                                                   float* __restrict__ attn_o){
  __shared__ float L[8 * 1536];
  __shared__ float Ps[96][8];
  const int t = blockIdx.x, tid = threadIdx.x;
  const float* src = qkv + (size_t)t * 8 * 2304;
  for (int i = tid; i < 3072; i += 128){
    const int e = i / 384, c4 = i - e * 384;
    ((float4*)L)[i] = ((const float4*)(src + (size_t)e * 2304))[c4];
  }
  __syncthreads();
  if (tid < 96){
    const int h = tid >> 3, e = tid & 7;
    const float* q = L + e * 1536 + h * 64;
    float s[8]; float mx = -1e30f;
    #pragma unroll
    for (int e2 = 0; e2 < 8; e2++){
      const float* kk = L + e2 * 1536 + 768 + h * 64;
      float acc = 0.f;
      #pragma unroll
      for (int d = 0; d < 64; d++) acc = fmaf(q[d], kk[d], acc);
      s[e2] = acc * 0.125f;
      mx = fmaxf(mx, s[e2]);
    }
    float den = 0.f;
    #pragma unroll
    for (int e2 = 0; e2 < 8; e2++){ s[e2] = expf(s[e2] - mx); den += s[e2]; }
    const float inv = 1.f / den;
    #pragma unroll
    for (int e2 = 0; e2 < 8; e2++) Ps[tid][e2] = s[e2] * inv;
  }
  __syncthreads();
  for (int i = tid; i < 1536; i += 128){
    const int e = i / 192, c4 = i - e * 192;
    ((float4*)L)[i] = ((const float4*)(src + (size_t)e * 2304 + 1536))[c4];
  }
  __syncthreads();
  if (tid < 96){
    const int h = tid >> 3, e = tid & 7;
    float p[8];
    #pragma unroll
    for (int e2 = 0; e2 < 8; e2++) p[e2] = Ps[tid][e2];
    float* dst = attn_o + ((size_t)t * 8 + e) * 768 + h * 64;
    for (int d = 0; d < 64; d++){
      float acc = 0.f;
      #pragma unroll
      for (int e2 = 0; e2 < 8; e2++) acc = fmaf(p[e2], L[e2 * 768 + h * 64 + d], acc);
      dst[d] = acc;
    }
  }
}

// ---------- router tail (per 256-token chunk) ----------
__global__ __launch_bounds__(256) void router_final(
    const float* __restrict__ proj, const float* __restrict__ eoc,
    const float* __restrict__ rnw, const float* __restrict__ gw,
    int t0, float* __restrict__ usage, float* __restrict__ tkp,
    u16* __restrict__ sf, float* __restrict__ oidx)
{
  const int tl = blockIdx.x, t = t0 + tl, tid = threadIdx.x;
  __shared__ float red[4];
  __shared__ float lg[8];
  __shared__ int sidx[2];
  __shared__ float csum[768];
  for (int i = tid; i < 768; i += 256) csum[i] = 0.f;
  __syncthreads();
  for (int e = 0; e < 8; e++){
    const float* pr = proj + ((size_t)tl * 8 + e) * 768;
    const float* er = eoc  + ((size_t)tl * 8 + e) * 768;
    float v[3]; float ss = 0.f;
    #pragma unroll
    for (int i = 0; i < 3; i++){ const int c = tid + i * 256; v[i] = pr[c] + er[c]; ss += v[i] * v[i]; }
    ss = blockReduceSum<4>(ss, red);
    const float sc = 1.f / sqrtf(ss * (1.f / 768.f) + 1e-5f);
    #pragma unroll
    for (int i = 0; i < 3; i++){ const int c = tid + i * 256; csum[c] += v[i] * sc * rnw[c]; }
  }
  for (int j = 0; j < 8; j++){
    float p = 0.f;
    #pragma unroll
    for (int i = 0; i < 3; i++){ const int c = tid + i * 256; p += csum[c] * gw[j * 768 + c]; }
    p = blockReduceSum<4>(p, red);
    if (tid == 0) lg[j] = p * 0.125f;
  }
  __syncthreads();
  if (tid == 0){
    float mx = -1e30f;
    for (int j = 0; j < 8; j++) mx = fmaxf(mx, lg[j]);
    float ex[8], den = 0.f;
    for (int j = 0; j < 8; j++){ ex[j] = expf(lg[j] - mx); den += ex[j]; }
    const float inv = 1.f / den;
    for (int j = 0; j < 8; j++) atomicAdd(&usage[j], ex[j] * inv);
    int i0 = 0; float l0 = lg[0];
    for (int j = 1; j < 8; j++) if (lg[j] > l0){ l0 = lg[j]; i0 = j; }
    int i1 = -1; float l1 = -1e30f;
    for (int j = 0; j < 8; j++) if (j != i0 && lg[j] > l1){ l1 = lg[j]; i1 = j; }
    const float e1 = expf(l1 - l0);
    const float p0 = 1.f / (1.f + e1);
    tkp[(size_t)t * 2]     = p0;
    tkp[(size_t)t * 2 + 1] = e1 * p0;
    sidx[0] = i0; sidx[1] = i1;
    oidx[(size_t)t * 2]     = (float)i0;
    oidx[(size_t)t * 2 + 1] = (float)i1;
  }
  __syncthreads();
  const int i0 = sidx[0], i1 = sidx[1];
  #pragma unroll
  for (int i = 0; i < 3; i++){
    const int c = tid + i * 256;
    sf[((size_t)t * 2 + 0) * 768 + c] = f2b(eoc[((size_t)tl * 8 + i0) * 768 + c]);
    sf[((size_t)t * 2 + 1) * 768 + c] = f2b(eoc[((size_t)tl * 8 + i1) * 768 + c]);
  }
}

// ---------- collaborative attention: L=2, 2 heads, hd=384 (fp32 io) ----------
__global__ __launch_bounds__(128) void collab_attn(
    const float* __restrict__ qkv, float* __restrict__ attn_o, float* __restrict__ divsum)
{
  const int t = blockIdx.x, tid = threadIdx.x;
  __shared__ float L[4608];
  __shared__ float P[8];
  __shared__ float red[2];
  const float* src = qkv + (size_t)t * 4608;
  for (int i = tid; i < 4608; i += 128) L[i] = src[i];
  __syncthreads();
  for (int hij = 0; hij < 8; hij++){
    const int h = hij >> 2, qi = (hij >> 1) & 1, kj = hij & 1;
    const float* q = L + qi * 2304 + h * 384;
    const float* k = L + kj * 2304 + 768 + h * 384;
    float acc = 0.f;
    for (int d = tid; d < 384; d += 128) acc += q[d] * k[d];
    acc = blockReduceSum<2>(acc, red);
    if (tid == 0) P[hij] = acc;
  }
  __syncthreads();
  if (tid == 0){
    const float scale = 0.051031036307982884f;
    float aw[2][2] = {{0.f,0.f},{0.f,0.f}};
    for (int h = 0; h < 2; h++)
      for (int i = 0; i < 2; i++){
        const float s0 = P[h*4 + i*2 + 0] * scale, s1 = P[h*4 + i*2 + 1] * scale;
        const float m = fmaxf(s0, s1);
        const float e0 = expf(s0 - m), e1 = expf(s1 - m), inv = 1.f / (e0 + e1);
        P[h*4 + i*2 + 0] = e0 * inv; P[h*4 + i*2 + 1] = e1 * inv;
        aw[i][0] += 0.5f * e0 * inv; aw[i][1] += 0.5f * e1 * inv;
      }
    float ent = 0.f;
    for (int i = 0; i < 2; i++)
      for (int j = 0; j < 2; j++) ent -= aw[i][j] * logf(aw[i][j] + 1e-9f);
    atomicAdd(divsum, ent);
  }
  __syncthreads();
  for (int c = tid; c < 768; c += 128){
    const int h = c / 384;
    const float v0 = L[1536 + c], v1 = L[3840 + c];
    attn_o[((size_t)t * 2 + 0) * 768 + c] = P[h*4 + 0] * v0 + P[h*4 + 1] * v1;
    attn_o[((size_t)t * 2 + 1) * 768 + c] = P[h*4 + 2] * v0 + P[h*4 + 3] * v1;
  }
}

// ---------- RMS(a+b)*w -> fp32  (a fp32, b bf16-u16 residual) ----------
__global__ __launch_bounds__(256) void rms_k(const float* __restrict__ a, const u16* __restrict__ b,
                                             const float* __restrict__ wt, float* __restrict__ o){
  const int r = blockIdx.x, tid = threadIdx.x;
  __shared__ float red[4];
  float v[3]; float ss = 0.f;
  #pragma unroll
  for (int i = 0; i < 3; i++){
    const int c = tid + i * 256;
    v[i] = a[(size_t)r * 768 + c] + b2f(b[(size_t)r * 768 + c]);
    ss += v[i] * v[i];
  }
  ss = blockReduceSum<4>(ss, red);
  const float sc = 1.f / sqrtf(ss * (1.f / 768.f) + 1e-5f);
  #pragma unroll
  for (int i = 0; i < 3; i++){
    const int c = tid + i * 256;
    o[(size_t)r * 768 + c] = v[i] * sc * wt[c];
  }
}

// ---------- y[tl] = p0*refined[tl,0] + p1*refined[tl,1]  (quarter-local) ----------
__global__ void wsum(const float* __restrict__ refined, const float* __restrict__ tkp,
                     float* __restrict__ y){
  const int idx = blockIdx.x * 256 + threadIdx.x;   // exactly 1024*768
  const int t = idx / 768, c = idx - t * 768;
  const float r0 = refined[((size_t)t * 2) * 768 + c];
  const float r1 = refined[((size_t)t * 2 + 1) * 768 + c];
  y[idx] = tkp[t * 2] * r0 + tkp[t * 2 + 1] * r1;
}

// ---------- aux ----------
__global__ void aux_k(const float* __restrict__ usage, const float* __restrict__ divsum,
                      float* __restrict__ out){
  if (threadIdx.x == 0 && blockIdx.x == 0){
    float u[8], s = 0.f;
    for (int e = 0; e < 8; e++){ u[e] = usage[e] * (1.f / 4096.f); s += u[e]; }
    const float mean = s * 0.125f;
    float bal = 0.f;
    for (int e = 0; e < 8; e++){ const float d = u[e] - mean; bal += d * d; }
    bal *= 0.125f;
    const float div = divsum[0] * (1.f / 8192.f);
    out[0] = 0.1f * (0.01f * div + 0.01f * bal);
  }
}

__global__ void zero_k(float* p, int n){
  const int i = blockIdx.x * 64 + threadIdx.x;
  if (i < n) p[i] = 0.f;
}

// =====================================================================
extern "C" void kernel_launch(void* const* d_in, const int* in_sizes, int n_in,
                              void* d_out, int out_size, void* d_ws, size_t ws_size,
                              hipStream_t stream)
{
  (void)in_sizes; (void)n_in; (void)out_size; (void)ws_size;
  const float* x       = (const float*)d_in[0];   // (4096, 768)
  const float* w1      = (const float*)d_in[1];   // (8, 768, 2048)
  const float* w3      = (const float*)d_in[2];   // (8, 768, 2048)
  const float* w2      = (const float*)d_in[3];   // (8, 2048, 768)
  const float* r_in_w  = (const float*)d_in[4];   // (2304, 768)
  const float* r_in_b  = (const float*)d_in[5];
  const float* r_out_w = (const float*)d_in[6];   // (768, 768)
  const float* r_out_b = (const float*)d_in[7];
  const float* r_norm_w= (const float*)d_in[8];
  const float* gate_w  = (const float*)d_in[9];   // (8, 768)
  const float* c_in_w  = (const float*)d_in[10];
  const float* c_in_b  = (const float*)d_in[11];
  const float* c_out_w = (const float*)d_in[12];
  const float* c_out_b = (const float*)d_in[13];
  const float* c_norm_w= (const float*)d_in[14];
  const float* ffn_w1  = (const float*)d_in[15];
  const float* ffn_w2  = (const float*)d_in[16];
  const float* o_w     = (const float*)d_in[17];

  // ---- workspace layout (52,461,824 B — identical extent to round 3) ----
  char* wsb   = (char*)d_ws;
  char* arena = wsb;                        // 33,554,432 B, time-shared
  float* eoc  = (float*)(wsb + 33554432);   //  6,291,456 B : chunk expert_out fp32 (256 tok x 8 x 768)
  u16*   sf   = (u16*)  (wsb + 39845888);   // 12,582,912 B : gathered experts bf16 (8192 x 768)
  float* tkp  = (float*)(wsb + 52428800);   //     32,768 B : top-2 probs
  float* usage= (float*)(wsb + 52461568);   //        256 B : usage[8] + divsum at [8]

  // Phase-A aliases (fp32): gate/up first; qkv/attn/proj reuse after w2.
  float* gateb = (float*)(arena);             // 16,777,216 B (8 x 256 x 2048)
  float* upb   = (float*)(arena + 16777216);  // 16,777,216 B
  float* qkvr  = (float*)(arena);             // 18,874,368 B (2048 x 2304)
  float* aor   = (float*)(arena + 18874368);  //  6,291,456 B (2048 x 768)
  float* projr = (float*)(arena + 25165824);  //  6,291,456 B -> 31,457,280 OK

  // Phase-B aliases (fp32, per 1024-token quarter = 2048 rows)
  float* qkvc  = (float*)(arena);             // 18,874,368 B (2048 x 2304)
  float* aoc   = (float*)(arena + 18874368);  //  6,291,456 B
  float* projc = (float*)(arena + 25165824);  //  6,291,456 B -> 31,457,280 OK
  float* aob   = (float*)(arena);             //  6,291,456 B (qkvc dead)
  float* t1b   = (float*)(arena + 6291456);   //  6,291,456 B
  float* refb  = (float*)(arena + 12582912);  //  6,291,456 B -> 18,874,368
  float* ybuf  = (float*)(arena + 18874368);  //  3,145,728 B (aoc dead)

  float* outp    = (float*)d_out;
  float* out_aux = outp + (size_t)4096*768;
  float* out_idx = out_aux + 1;

  zero_k<<<1, 64, 0, stream>>>(usage, 16);

  // -------- Phase A: logits path (split-fp16 MFMA), 16 chunks x 256 tokens ----
  for (int cch = 0; cch < 16; cch++){
    const int t0 = cch * 256;
    // gate & up in one dual dispatch: z<8 -> w1/gateb, z>=8 -> w3/upb
    mgemm<0,true,false,false,0,false,true><<<dim3(16,2,16),256,0,stream>>>(
      x + (size_t)t0*768, 768, 0LL,
      w1, w3, 2048, 1572864LL,
      gateb, upb, 2048, 524288LL,
      nullptr, nullptr, 0, 768, 8);
    silu_k<<<16384, 256, 0, stream>>>(gateb, upb, gateb, 4194304);
    // expert_out -> eoc rows (tok*8+e) via ldc=6144, strideC=768
    mgemm<0,true,false,false,0,false,false><<<dim3(6,2,8),256,0,stream>>>(
      gateb, 2048, 524288LL,
      w2, nullptr, 768, 1572864LL,
      eoc, nullptr, 6144, 768LL,
      nullptr, nullptr, 0, 2048, 0);
    // router qkv = eoc @ r_in_w^T + b  (2048 rows)
    mgemm<0,true,true,true,0,false,false><<<dim3(18,16,1),256,0,stream>>>(
      eoc, 768, 0LL, r_in_w, nullptr, 768, 0LL,
      qkvr, nullptr, 2304, 0LL, r_in_b, nullptr, 0, 768, 0);
    router_attn<<<256, 128, 0, stream>>>(qkvr, aor);
    mgemm<0,true,true,true,0,false,false><<<dim3(6,16,1),256,0,stream>>>(
      aor, 768, 0LL, r_out_w, nullptr, 768, 0LL,
      projr, nullptr, 768, 0LL, r_out_b, nullptr, 0, 768, 0);
    router_final<<<256, 256, 0, stream>>>(projr, eoc, r_norm_w, gate_w, t0,
                                          usage, tkp, sf, out_idx);
  }

  // -------- Phase B: collab path (1-pass fp16 MFMA), 4 quarters x 1024 tokens ----
  for (int q = 0; q < 4; q++){
    const int tq0 = q * 1024;
    const u16* sf_q = sf + (size_t)tq0 * 2 * 768;
    mgemm<1,false,true,true,0,false,false><<<dim3(18,16,1),256,0,stream>>>(
      sf_q, 768, 0LL, c_in_w, nullptr, 768, 0LL,
      qkvc, nullptr, 2304, 0LL, c_in_b, nullptr, 0, 768, 0);
    collab_attn<<<1024, 128, 0, stream>>>(qkvc, aoc, usage + 8);
    mgemm<0,false,true,true,0,false,false><<<dim3(6,16,1),256,0,stream>>>(
      aoc, 768, 0LL, c_out_w, nullptr, 768, 0LL,
      projc, nullptr, 768, 0LL, c_out_b, nullptr, 0, 768, 0);
    rms_k<<<2048, 256, 0, stream>>>(projc, sf_q, c_norm_w, aob);
    // t1 = gelu(ao @ ffn_w1^T)
    mgemm<0,false,true,false,1,false,false><<<dim3(6,16,1),256,0,stream>>>(
      aob, 768, 0LL, ffn_w1, nullptr, 768, 0LL,
      t1b, nullptr, 768, 0LL, nullptr, nullptr, 0, 768, 0);
    // refined = t1 @ ffn_w2^T + ao
    mgemm<0,false,true,false,0,true,false><<<dim3(6,16,1),256,0,stream>>>(
      t1b, 768, 0LL, ffn_w2, nullptr, 768, 0LL,
      refb, nullptr, 768, 0LL, nullptr, aob, 768, 768, 0);
    wsum<<<3072, 256, 0, stream>>>(refb, tkp + (size_t)tq0 * 2, ybuf);
    // final = y @ o_w^T -> d_out
    mgemm<0,false,true,false,0,false,false><<<dim3(6,8,1),256,0,stream>>>(
      ybuf, 768, 0LL, o_w, nullptr, 768, 0LL,
      outp + (size_t)tq0 * 768, nullptr, 768, 0LL, nullptr, nullptr, 0, 768, 0);
  }
  aux_k<<<1, 64, 0, stream>>>(usage, usage + 8, out_aux);
}